// Round 4
// baseline (781.949 us; speedup 1.0000x reference)
//
#include <hip/hip_runtime.h>
#include <math.h>

#define BN_EPS 1e-5f
constexpr int COUT = 256;     // output channels of both linears
constexpr int ROWS = 32;      // rows per GEMM block
constexpr int KCH  = 128;     // K-chunk staged in LDS
constexpr int CHUNK = 2048;   // candidate points staged per KNN chunk (32 KB)

// ---------------------------------------------------------------------------
// GEMM  out[M][256] = relu( (X[M][K] @ W[256][K]^T + b) * scale + shift )
// optionally += interp gather from f2 via (wts, idx)
// block = 256 threads (one per output column), each block does ROWS rows.
// ---------------------------------------------------------------------------
__global__ __launch_bounds__(256) void gemm_bn_relu_k(
    const float* __restrict__ X, const float* __restrict__ W,
    const float* __restrict__ b, const float* __restrict__ g,
    const float* __restrict__ beta, const float* __restrict__ m,
    const float* __restrict__ v,
    float* __restrict__ out, int M, int K,
    const float* __restrict__ f2,      // nullable: interp source (N2 x 256)
    const float4* __restrict__ wts,    // per-query 3 weights
    const int4* __restrict__ idx)      // per-query 3 global rows into f2
{
    const int tid  = threadIdx.x;            // output column
    const int row0 = blockIdx.x * ROWS;
    __shared__ float At[ROWS][KCH];

    float acc[ROWS];
#pragma unroll
    for (int r = 0; r < ROWS; ++r) acc[r] = 0.f;

    const float* wp_base = W + (long)tid * K;

    for (int k0 = 0; k0 < K; k0 += KCH) {
        // stage A tile (ROWS x KCH) with float4 coalesced loads
        for (int i = tid; i < ROWS * (KCH / 4); i += 256) {
            int r = i >> 5;            // KCH/4 = 32 float4 per row
            int c = (i & 31) * 4;
            *(float4*)&At[r][c] =
                *(const float4*)&X[(long)(row0 + r) * K + k0 + c];
        }
        __syncthreads();

        const float* wp = wp_base + k0;
        for (int k = 0; k < KCH; k += 4) {
            const float4 wv = *(const float4*)(wp + k);
#pragma unroll
            for (int r = 0; r < ROWS; ++r) {
                const float4 a = *(const float4*)(&At[r][k]);
                acc[r] = fmaf(a.x, wv.x, acc[r]);
                acc[r] = fmaf(a.y, wv.y, acc[r]);
                acc[r] = fmaf(a.z, wv.z, acc[r]);
                acc[r] = fmaf(a.w, wv.w, acc[r]);
            }
        }
        __syncthreads();
    }

    // BN fold: y = (acc + bias - m)*g*rsqrt(v+eps) + beta
    const float s    = g[tid] * rsqrtf(v[tid] + BN_EPS);
    const float sh   = beta[tid] - m[tid] * s;
    const float bias = b[tid];

    for (int r = 0; r < ROWS; ++r) {
        const int q = row0 + r;
        if (q >= M) break;
        float y = (acc[r] + bias) * s + sh;
        y = fmaxf(y, 0.f);
        if (f2) {
            const float4 w4 = wts[q];
            const int4  i4 = idx[q];
            y += w4.x * f2[(long)i4.x * COUT + tid]
               + w4.y * f2[(long)i4.y * COUT + tid]
               + w4.z * f2[(long)i4.z * COUT + tid];
        }
        out[(long)q * COUT + tid] = y;
    }
}

// ---------------------------------------------------------------------------
// 3-NN per query. d2 replicates the numpy/XLA float32 arithmetic BIT-EXACTLY:
//   qq = fl(fl(fl(qx^2)+fl(qy^2))+fl(qz^2))   (squares rounded separately)
//   pp = same
//   dot = fmaf(q2,p2, fmaf(q1,p1, fl(q0*p0)))  (sgemm K=3 fma chain from 0)
//   d2 = fl(fl(qq+pp) - fl(2*dot))
// Strict-< insertion => lowest-index-first on exact ties (stable top_k).
// __f*_rn intrinsics are never contracted/reassociated by the compiler.
// ---------------------------------------------------------------------------
__global__ __launch_bounds__(256) void knn3_k(
    const float* __restrict__ P1, const float* __restrict__ P2,
    const int* __restrict__ rs1, const int* __restrict__ rs2, int B,
    float4* __restrict__ wts, int4* __restrict__ idxout, int N1)
{
    __shared__ float4 Pt[CHUNK];   // (x, y, z, pp) with pp in np rounding

    int q = blockIdx.x * blockDim.x + threadIdx.x;
    if (q >= N1) q = N1 - 1;   // benign duplicate work at tail

    // segment lookup (B is tiny; uniform per block since segments are
    // multiples of the block size)
    int seg = 0;
    while (seg + 1 < B && q >= rs1[seg + 1]) ++seg;
    const int pstart = rs2[seg];
    const int pend   = rs2[seg + 1];

    const float qx = P1[q * 3 + 0];
    const float qy = P1[q * 3 + 1];
    const float qz = P1[q * 3 + 2];
    const float qq = __fadd_rn(__fadd_rn(__fmul_rn(qx, qx), __fmul_rn(qy, qy)),
                               __fmul_rn(qz, qz));

    float b0 = 3.4e38f, b1 = 3.4e38f, b2 = 3.4e38f;
    int   i0 = pstart,  i1 = pstart,  i2 = pstart;

    for (int c0 = pstart; c0 < pend; c0 += CHUNK) {
        const int cnt = min(CHUNK, pend - c0);
        __syncthreads();
        for (int i = threadIdx.x; i < cnt; i += blockDim.x) {
            const float px = P2[(long)(c0 + i) * 3 + 0];
            const float py = P2[(long)(c0 + i) * 3 + 1];
            const float pz = P2[(long)(c0 + i) * 3 + 2];
            const float pp = __fadd_rn(
                __fadd_rn(__fmul_rn(px, px), __fmul_rn(py, py)),
                __fmul_rn(pz, pz));
            Pt[i] = make_float4(px, py, pz, pp);
        }
        __syncthreads();

        for (int j = 0; j < cnt; ++j) {
            const float4 p = Pt[j];                    // LDS broadcast b128
            const float dot = fmaf(qz, p.z, fmaf(qy, p.y, __fmul_rn(qx, p.x)));
            const float d2  = __fsub_rn(__fadd_rn(qq, p.w),
                                        __fmul_rn(2.0f, dot));
            if (d2 < b2) {                             // strict <: stable ties
                const int gj = c0 + j;
                if (d2 < b1) {
                    b2 = b1; i2 = i1;
                    if (d2 < b0) { b1 = b0; i1 = i0; b0 = d2; i0 = gj; }
                    else         { b1 = d2; i1 = gj; }
                } else { b2 = d2; i2 = gj; }
            }
        }
    }

    // weights in f32, replicating np: w = 1/(max(d,0)+1e-8), w /= sum(w)
    const float d0 = fmaxf(b0, 0.f);
    const float d1 = fmaxf(b1, 0.f);
    const float d2v = fmaxf(b2, 0.f);
    const float w0 = __fdiv_rn(1.0f, __fadd_rn(d0, 1e-8f));
    const float w1 = __fdiv_rn(1.0f, __fadd_rn(d1, 1e-8f));
    const float w2 = __fdiv_rn(1.0f, __fadd_rn(d2v, 1e-8f));
    const float wsum = __fadd_rn(__fadd_rn(w0, w1), w2);
    wts[q]    = make_float4(__fdiv_rn(w0, wsum), __fdiv_rn(w1, wsum),
                            __fdiv_rn(w2, wsum), 0.f);
    idxout[q] = make_int4(i0, i1, i2, 0);
}

// ---------------------------------------------------------------------------
extern "C" void kernel_launch(void* const* d_in, const int* in_sizes, int n_in,
                              void* d_out, int out_size, void* d_ws, size_t ws_size,
                              hipStream_t stream) {
    const float* P1   = (const float*)d_in[0];
    const float* F1   = (const float*)d_in[1];
    const int*   rs1  = (const int*)  d_in[2];
    const float* P2   = (const float*)d_in[3];
    const float* F2in = (const float*)d_in[4];
    const int*   rs2  = (const int*)  d_in[5];
    const float* w1   = (const float*)d_in[6];
    const float* b1   = (const float*)d_in[7];
    const float* g1   = (const float*)d_in[8];
    const float* be1  = (const float*)d_in[9];
    const float* m1   = (const float*)d_in[10];
    const float* v1   = (const float*)d_in[11];
    const float* w2   = (const float*)d_in[12];
    const float* b2   = (const float*)d_in[13];
    const float* g2   = (const float*)d_in[14];
    const float* be2  = (const float*)d_in[15];
    const float* m2   = (const float*)d_in[16];
    const float* v2   = (const float*)d_in[17];

    const int N1   = in_sizes[0] / 3;      // 65536
    const int N2   = in_sizes[3] / 3;      // 16384
    const int CIN  = in_sizes[4] / N2;     // 512
    const int B    = in_sizes[2] - 1;      // 4

    float*  f2  = (float*)d_ws;                                      // N2 x 256
    float4* wts = (float4*)((char*)d_ws + (size_t)N2 * COUT * 4);    // N1 float4
    int4*   idx = (int4*)((char*)wts + (size_t)N1 * sizeof(float4)); // N1 int4

    // KNN weights/indices (independent of features)
    knn3_k<<<(N1 + 255) / 256, 256, 0, stream>>>(P1, P2, rs1, rs2, B, wts, idx, N1);

    // f2 = relu(bn(feat_2 @ w2^T + b2))
    gemm_bn_relu_k<<<(N2 + ROWS - 1) / ROWS, 256, 0, stream>>>(
        F2in, w2, b2, g2, be2, m2, v2, f2, N2, CIN,
        nullptr, nullptr, nullptr);

    // out = relu(bn(feat_1 @ w1^T + b1)) + interp
    gemm_bn_relu_k<<<(N1 + ROWS - 1) / ROWS, 256, 0, stream>>>(
        F1, w1, b1, g1, be1, m1, v1, (float*)d_out, N1, COUT,
        f2, wts, idx);
}